// Round 4
// baseline (118.123 us; speedup 1.0000x reference)
//
#include <hip/hip_runtime.h>
#include <stdint.h>

// Problem constants (from the reference)
constexpr int Tdim = 4096;   // time / input width
constexpr int Ndim = 4096;   // neurons
constexpr int Bdim = 1024;   // batch
constexpr int NB   = 16;     // address bits
constexpr int WPN  = 2115;   // words per neuron = ceil(65536 / 31)

// ---------------------------------------------------------------------------
// Layout detection: if an integer input is int64 on device (values < 2^31),
// every odd int32 position is a zero high-half. Check 64 odd positions per
// array; all-zero => int64 layout (flag=1). False positive <= 2^-64 (x is
// random 0/1 per int32 slot in int32 layout; conn/mem random large values).
// flags[0]=x, flags[1]=conn, flags[2]=mem.
// ---------------------------------------------------------------------------
__global__ __launch_bounds__(64) void detect_kernel(const int* __restrict__ x,
                                                    const int* __restrict__ conn,
                                                    const int* __restrict__ mem,
                                                    int* __restrict__ flags) {
    const int j = threadIdx.x;                 // 0..63
    const unsigned long long bx = __ballot(x[2 * j + 1] == 0);
    const unsigned long long bc = __ballot(conn[2 * j + 1] == 0);
    const unsigned long long bm = __ballot(mem[2 * j + 1] == 0);
    if (j == 0) {
        flags[0] = (bx == ~0ull) ? 1 : 0;
        flags[1] = (bc == ~0ull) ? 1 : 0;
        flags[2] = (bm == ~0ull) ? 1 : 0;
    }
}

// ---------------------------------------------------------------------------
// Kernel 1: pack x (B x T of 0/1) into bit-planes:
//   xT[bg * T + t] = uint32 whose bit bl = x[(bg*32 + bl) * T + t]
// sx = int32-index multiplier (2 if x is int64: low half holds the value).
// Coalesced reads (lane = t), 32 strided rows per thread.
// ---------------------------------------------------------------------------
__global__ __launch_bounds__(256) void pack_kernel(const int* __restrict__ x,
                                                   uint32_t* __restrict__ xT,
                                                   const int* __restrict__ flags) {
    const int sx = flags[0] ? 2 : 1;
    const int t  = blockIdx.x * 256 + threadIdx.x;
    const int bg = blockIdx.y;
    uint32_t w = 0;
#pragma unroll
    for (int bl = 0; bl < 32; ++bl) {
        const size_t idx = ((size_t)(bg * 32 + bl) * Tdim + t) * sx;
        w |= (uint32_t)(x[idx] & 1) << bl;
    }
    xT[(size_t)bg * Tdim + t] = w;
}

// ---------------------------------------------------------------------------
// Kernel 2: one thread = one neuron x 64 batches.
//  - load 16 connection indices (layout-flag-aware)
//  - gather 16 words from each of two 32-batch bit-plane slices (16 KB, L2-hot)
//  - 32x32 in-register bit transpose -> 64 16-bit addresses (~7.5 VALU/addr)
//  - 64 independent gathers into this neuron's memory row (deep MLP)
//  - 64 wave-coalesced INT32 stores (harness reads d_out as np.int32)
//
// Transpose convention (Hacker's Delight delta-swap, re-derived):
//   r[k] bit q = a_in[31-q] bit (31-k)
// With a[j] = wB[j] (batches 32..63), a[16+j] = wA[j] (batches 0..31):
//   r[k] = (addrB[31-k] << 16) | addrA[31-k]
// ---------------------------------------------------------------------------
__global__ __launch_bounds__(64) void lookup_kernel(const uint32_t* __restrict__ xT,
                                                    const int* __restrict__ conn,
                                                    const int* __restrict__ mem,
                                                    int* __restrict__ out,
                                                    const int* __restrict__ flags) {
    const int sc = flags[1] ? 2 : 1;           // conn int32-index multiplier
    const int sm = flags[2] ? 2 : 1;           // mem  int32-index multiplier
    const int n  = blockIdx.x * 64 + threadIdx.x;
    const int by = blockIdx.y;                 // 64-batch group

    const uint32_t* xA = xT + (size_t)(by * 2) * Tdim;   // batches by*64 .. +31
    const uint32_t* xB = xA + Tdim;                      // batches by*64+32 .. +63

    const int* cp = conn + (size_t)n * NB * sc;
    uint32_t a[32];
#pragma unroll
    for (int j = 0; j < 16; ++j) {
        const int c = cp[j * sc];              // connection j, value < 4096
        a[16 + j] = xA[c];
        a[j]      = xB[c];
    }

    // 32x32 bit transpose, fully unrolled (all indices compile-time -> registers)
#pragma unroll
    for (int j = 16; j != 0; j >>= 1) {
        const uint32_t m = 0xFFFFFFFFu / ((1u << j) + 1u);
#pragma unroll
        for (int k = 0; k < 32; ++k) {
            if ((k & j) == 0) {
                const uint32_t t = (a[k] ^ (a[k + j] >> j)) & m;
                a[k]     ^= t;
                a[k + j] ^= t << j;
            }
        }
    }

    const int* mrow = mem + (size_t)n * WPN * sm;
    int* orow = out + (size_t)by * 64 * Ndim + n;

#pragma unroll
    for (int k = 0; k < 32; ++k) {
        const uint32_t rw  = a[k];
        const uint32_t adA = rw & 0xFFFFu;
        const uint32_t adB = rw >> 16;
        const uint32_t wiA = adA / 31u;              // magic-mul, no div instr
        const uint32_t shA = (adA - wiA * 31u) * 2u; // 0..60; >=32 lands in zero bits
        const uint32_t wiB = adB / 31u;
        const uint32_t shB = (adB - wiB * 31u) * 2u;
        // int64 layout: low half of word wi at int32 index 2*wi (high half zero,
        // matching the reference's zero bits 31..62). int32 layout: index wi.
        const uint64_t wdA = (uint32_t)mrow[(size_t)wiA * sm];
        const uint64_t wdB = (uint32_t)mrow[(size_t)wiB * sm];
        const int kb = 31 - k;                       // batch index within the 64-group
        orow[(size_t)kb * Ndim]        = (int)((wdA >> shA) & 3u);
        orow[(size_t)(kb + 32) * Ndim] = (int)((wdB >> shB) & 3u);
    }
}

// ---------------------------------------------------------------------------
// Fallback (only if ws_size is too small for bit-planes): one thread per
// (b, n) output, direct gather of 16 x-bits. Correct but slower.
// ---------------------------------------------------------------------------
__global__ __launch_bounds__(256) void direct_kernel(const int* __restrict__ x,
                                                     const int* __restrict__ conn,
                                                     const int* __restrict__ mem,
                                                     int* __restrict__ out,
                                                     const int* __restrict__ flags) {
    const int sx = flags[0] ? 2 : 1;
    const int sc = flags[1] ? 2 : 1;
    const int sm = flags[2] ? 2 : 1;
    const int n  = blockIdx.x * 256 + threadIdx.x;   // lane = n -> coalesced store
    const int b  = blockIdx.y;
    const int* cp = conn + (size_t)n * NB * sc;
    const int* xr = x + (size_t)b * Tdim * sx;
    uint32_t addr = 0;
#pragma unroll
    for (int j = 0; j < 16; ++j) {
        const int c = cp[j * sc];
        addr = (addr << 1) | (uint32_t)(xr[(size_t)c * sx] & 1);
    }
    const uint32_t wi = addr / 31u;
    const uint32_t sh = (addr - wi * 31u) * 2u;
    const uint64_t wd = (uint32_t)mem[((size_t)n * WPN + wi) * sm];
    out[(size_t)b * Ndim + n] = (int)((wd >> sh) & 3u);
}

// ---------------------------------------------------------------------------
extern "C" void kernel_launch(void* const* d_in, const int* in_sizes, int n_in,
                              void* d_out, int out_size, void* d_ws, size_t ws_size,
                              hipStream_t stream) {
    const int* x    = (const int*)d_in[0];       // (B, T) 0/1
    const int* conn = (const int*)d_in[1];       // (N, 16) indices < T
    const int* mem  = (const int*)d_in[2];       // (N, WPN), values < 2^31
    int*       out  = (int*)d_out;               // (B, N), read back as np.int32
    int*       flags = (int*)d_ws;               // 3 layout flags (256 B block)
    uint32_t*  xT    = (uint32_t*)((char*)d_ws + 256);  // (B/32, T) planes, 512 KB

    detect_kernel<<<1, 64, 0, stream>>>(x, conn, mem, flags);

    const size_t need = 256 + (size_t)(Bdim / 32) * Tdim * sizeof(uint32_t);
    if (ws_size >= need) {
        dim3 g1(Tdim / 256, Bdim / 32);          // 16 x 32 = 512 blocks
        pack_kernel<<<g1, 256, 0, stream>>>(x, xT, flags);
        dim3 g2(Ndim / 64, Bdim / 64);           // 64 x 16 = 1024 blocks
        lookup_kernel<<<g2, 64, 0, stream>>>(xT, conn, mem, out, flags);
    } else {
        dim3 g3(Ndim / 256, Bdim);               // 16 x 1024 blocks
        direct_kernel<<<g3, 256, 0, stream>>>(x, conn, mem, out, flags);
    }
}